// Round 2
// baseline (1732.110 us; speedup 1.0000x reference)
//
#include <hip/hip_runtime.h>

// ---------------------------------------------------------------------------
// GCN: 3x GCNConv(9->16->16->16) + MLP(concat 25 ->128->128->1), N=250000,
// E=5,000,000 edges + self loops. f32 in/out; edge_index int32 OR int64
// (detected on device). CSR-by-dst gather aggregation (no float atomics) +
// register-blocked MLP.
// ---------------------------------------------------------------------------

__global__ __launch_bounds__(64) void k_detect(const void* __restrict__ edges,
                                               int* __restrict__ flag, int n_nodes)
{
    if (threadIdx.x == 0 && blockIdx.x == 0) {
        const long long* p = (const long long*)edges;
        int is64 = 1;
        for (int i = 0; i < 16; ++i) {
            long long v = p[i];
            if (v < 0 || v >= (long long)n_nodes) is64 = 0;
        }
        *flag = is64;
    }
}

__global__ __launch_bounds__(256) void k_convert(const void* __restrict__ edges,
                                                 const int* __restrict__ flag,
                                                 int* __restrict__ out, long long total)
{
    long long i = (long long)blockIdx.x * 256 + threadIdx.x;
    if (i >= total) return;
    if (*flag) out[i] = (int)((const long long*)edges)[i];
    else       out[i] = ((const int*)edges)[i];
}

__global__ __launch_bounds__(256) void k_hist(const int* __restrict__ dst,
                                              int* __restrict__ degi, long long e)
{
    long long i = (long long)blockIdx.x * 256 + threadIdx.x;
    if (i < e) atomicAdd(&degi[dst[i]], 1);
}

// exclusive scan, stage 1: per-256-chunk scan + per-block totals
__global__ __launch_bounds__(256) void k_scan1(const int* __restrict__ degi,
                                               int* __restrict__ excl,
                                               int* __restrict__ partials, int n)
{
    __shared__ int s[256];
    int tid = threadIdx.x;
    int i = blockIdx.x * 256 + tid;
    int v = (i < n) ? degi[i] : 0;
    s[tid] = v;
    __syncthreads();
#pragma unroll
    for (int off = 1; off < 256; off <<= 1) {
        int t = (tid >= off) ? s[tid - off] : 0;
        __syncthreads();
        s[tid] += t;
        __syncthreads();
    }
    if (i < n) excl[i] = s[tid] - v;          // exclusive within chunk
    if (tid == 255) partials[blockIdx.x] = s[255];
}

// stage 2: single block, exclusive scan of partials (any nb, carry loop)
__global__ __launch_bounds__(1024) void k_scan2(int* __restrict__ p, int nb)
{
    __shared__ int s[1024];
    __shared__ int carry_s;
    int t = threadIdx.x;
    if (t == 0) carry_s = 0;
    __syncthreads();
    for (int base = 0; base < nb; base += 1024) {
        int idx = base + t;
        int v = (idx < nb) ? p[idx] : 0;
        s[t] = v;
        __syncthreads();
        for (int off = 1; off < 1024; off <<= 1) {
            int u = (t >= off) ? s[t - off] : 0;
            __syncthreads();
            s[t] += u;
            __syncthreads();
        }
        int carry = carry_s;
        if (idx < nb) p[idx] = carry + s[t] - v;
        __syncthreads();
        if (t == 0) carry_s += s[1023];
        __syncthreads();
    }
}

// stage 3: add block offsets; produce row_off and cursor copy
__global__ __launch_bounds__(256) void k_scan3(int* __restrict__ row_off,
                                               int* __restrict__ cursor,
                                               const int* __restrict__ partials, int n)
{
    int i = blockIdx.x * 256 + threadIdx.x;
    if (i < n) {
        int v = row_off[i] + partials[blockIdx.x];
        row_off[i] = v;
        cursor[i]  = v;
    }
}

__global__ __launch_bounds__(256) void k_dinv(const int* __restrict__ degi,
                                              float* __restrict__ dinv, int n)
{
    int i = blockIdx.x * 256 + threadIdx.x;
    if (i < n) dinv[i] = rsqrtf((float)(degi[i] + 1));   // +1 self loop
}

__global__ __launch_bounds__(256) void k_fill(const int* __restrict__ src,
                                              const int* __restrict__ dst,
                                              int* __restrict__ cursor,
                                              int* __restrict__ ssrc, long long e)
{
    long long i = (long long)blockIdx.x * 256 + threadIdx.x;
    if (i >= e) return;
    int d = dst[i];
    int pos = atomicAdd(&cursor[d], 1);
    ssrc[pos] = src[i];
}

// h = x @ W1 (9->16); hs = h * dinv
__global__ __launch_bounds__(256) void k_lin1(const float* __restrict__ x,
                                              const float* __restrict__ W1,
                                              const float* __restrict__ dinv,
                                              float* __restrict__ hs, int n)
{
    __shared__ float sW[144];
    if (threadIdx.x < 144) sW[threadIdx.x] = W1[threadIdx.x];
    __syncthreads();
    int i = blockIdx.x * 256 + threadIdx.x;
    if (i >= n) return;
    float xv[9];
#pragma unroll
    for (int k = 0; k < 9; ++k) xv[k] = x[(size_t)i * 9 + k];
    float di = dinv[i];
#pragma unroll
    for (int j = 0; j < 16; ++j) {
        float acc = 0.f;
#pragma unroll
        for (int k = 0; k < 9; ++k) acc = fmaf(xv[k], sW[k * 16 + j], acc);
        hs[(size_t)i * 16 + j] = acc * di;
    }
}

// t = relu(agg + bias); h = t @ W (16->16); hs = h * dinv
__global__ __launch_bounds__(256) void k_lin_mid(const float* __restrict__ bias,
                                                 const float* __restrict__ W,
                                                 const float* __restrict__ dinv,
                                                 const float* __restrict__ agg,
                                                 float* __restrict__ hs, int n)
{
    __shared__ float sW[256];
    __shared__ float sB[16];
    sW[threadIdx.x] = W[threadIdx.x];
    if (threadIdx.x < 16) sB[threadIdx.x] = bias[threadIdx.x];
    __syncthreads();
    int i = blockIdx.x * 256 + threadIdx.x;
    if (i >= n) return;
    float t[16];
#pragma unroll
    for (int k = 0; k < 16; ++k) {
        float v = agg[(size_t)i * 16 + k] + sB[k];
        t[k] = v > 0.f ? v : 0.f;
    }
    float di = dinv[i];
#pragma unroll
    for (int j = 0; j < 16; ++j) {
        float acc = 0.f;
#pragma unroll
        for (int k = 0; k < 16; ++k) acc = fmaf(t[k], sW[k * 16 + j], acc);
        hs[(size_t)i * 16 + j] = acc * di;
    }
}

// One wave per node. lane = slot*16+k (4 edge slots x 16 feats).
// agg[d][k] = dinv[d] * (hs[d][k] + sum_{e in CSR(d)} hs[src_e][k])
__global__ __launch_bounds__(256) void k_gather(const int* __restrict__ ssrc,
                                                const int* __restrict__ row_off,
                                                const int* __restrict__ degi,
                                                const float* __restrict__ dinv,
                                                const float* __restrict__ hs,
                                                float* __restrict__ agg, int n)
{
    int wid = (int)(((long long)blockIdx.x * 256 + threadIdx.x) >> 6);
    if (wid >= n) return;
    int lane = threadIdx.x & 63;
    int slot = lane >> 4;
    int k    = lane & 15;
    int start = row_off[wid];
    int deg   = degi[wid];
    float sum = (slot == 0) ? hs[(size_t)wid * 16 + k] : 0.f;   // self loop
    for (int e = slot; e < deg; e += 4) {
        int s = ssrc[start + e];
        sum += hs[(size_t)s * 16 + k];
    }
    sum += __shfl_xor(sum, 16);
    sum += __shfl_xor(sum, 32);
    if (slot == 0) agg[(size_t)wid * 16 + k] = sum * dinv[wid];
}

// MLP head: feat = [x(9), relu(agg3+b3)(16)]; z=relu(feat@Wl2+bl2);
// z2=relu(z@Wl3+bl3); out = z2@Wl4+bl4.
// 1024 threads = 16 waves; each wave owns an 8-node tile; lane = ng*16+og:
// og in [0,16) -> 8 consecutive outputs, ng in [0,4) -> 2 nodes.
__global__ __launch_bounds__(1024) void k_mlp(const float* __restrict__ x,
                                              const float* __restrict__ agg3,
                                              const float* __restrict__ b3,
                                              const float* __restrict__ Wl2,
                                              const float* __restrict__ bl2,
                                              const float* __restrict__ Wl3,
                                              const float* __restrict__ bl3,
                                              const float* __restrict__ Wl4,
                                              const float* __restrict__ bl4,
                                              float* __restrict__ out, int n)
{
    __shared__ __align__(16) float sW3[128 * 128];        // 64 KB
    __shared__ __align__(16) float zs[16][8][132];        // 66 KB (padded stride)
    __shared__ __align__(16) float sfeat[16][8][26];      // 13 KB
    __shared__ float sB2[128];
    __shared__ float sB3[128];
    __shared__ float sW4[128];

    int tid = threadIdx.x;
    for (int i = tid; i < 128 * 128 / 4; i += 1024)
        ((float4*)sW3)[i] = ((const float4*)Wl3)[i];
    if (tid < 128) { sB2[tid] = bl2[tid]; sB3[tid] = bl3[tid]; sW4[tid] = Wl4[tid]; }
    __syncthreads();
    float blast = bl4[0];

    int w    = tid >> 6;
    int lane = tid & 63;
    int og   = lane & 15;
    int ng   = lane >> 4;
    int ntiles = (n + 7) >> 3;

    for (int tile = blockIdx.x * 16 + w; tile < ntiles; tile += gridDim.x * 16) {
        int base = tile * 8;
        // stage features for 8 nodes (per-wave; no block barrier needed)
        for (int idx = lane; idx < 8 * 25; idx += 64) {
            int nn = idx / 25, f = idx - nn * 25;
            int node = base + nn;
            float v = 0.f;
            if (node < n) {
                if (f < 9) v = x[(size_t)node * 9 + f];
                else {
                    float t = agg3[(size_t)node * 16 + (f - 9)] + b3[f - 9];
                    v = t > 0.f ? t : 0.f;
                }
            }
            sfeat[w][nn][f] = v;
        }

        // layer l2: z[8][128] = feat[8][25] @ Wl2, relu -> zs
        float a[2][8];
#pragma unroll
        for (int i = 0; i < 2; ++i)
#pragma unroll
            for (int j = 0; j < 8; ++j) a[i][j] = sB2[og * 8 + j];
#pragma unroll
        for (int k = 0; k < 25; ++k) {
            float4 w0 = *(const float4*)&Wl2[k * 128 + og * 8];
            float4 w1 = *(const float4*)&Wl2[k * 128 + og * 8 + 4];
            float f0 = sfeat[w][ng * 2 + 0][k];
            float f1 = sfeat[w][ng * 2 + 1][k];
            a[0][0] = fmaf(f0, w0.x, a[0][0]); a[0][1] = fmaf(f0, w0.y, a[0][1]);
            a[0][2] = fmaf(f0, w0.z, a[0][2]); a[0][3] = fmaf(f0, w0.w, a[0][3]);
            a[0][4] = fmaf(f0, w1.x, a[0][4]); a[0][5] = fmaf(f0, w1.y, a[0][5]);
            a[0][6] = fmaf(f0, w1.z, a[0][6]); a[0][7] = fmaf(f0, w1.w, a[0][7]);
            a[1][0] = fmaf(f1, w0.x, a[1][0]); a[1][1] = fmaf(f1, w0.y, a[1][1]);
            a[1][2] = fmaf(f1, w0.z, a[1][2]); a[1][3] = fmaf(f1, w0.w, a[1][3]);
            a[1][4] = fmaf(f1, w1.x, a[1][4]); a[1][5] = fmaf(f1, w1.y, a[1][5]);
            a[1][6] = fmaf(f1, w1.z, a[1][6]); a[1][7] = fmaf(f1, w1.w, a[1][7]);
        }
#pragma unroll
        for (int i = 0; i < 2; ++i) {
            float4 lo, hi;
            lo.x = a[i][0] > 0.f ? a[i][0] : 0.f; lo.y = a[i][1] > 0.f ? a[i][1] : 0.f;
            lo.z = a[i][2] > 0.f ? a[i][2] : 0.f; lo.w = a[i][3] > 0.f ? a[i][3] : 0.f;
            hi.x = a[i][4] > 0.f ? a[i][4] : 0.f; hi.y = a[i][5] > 0.f ? a[i][5] : 0.f;
            hi.z = a[i][6] > 0.f ? a[i][6] : 0.f; hi.w = a[i][7] > 0.f ? a[i][7] : 0.f;
            *(float4*)&zs[w][ng * 2 + i][og * 8]     = lo;
            *(float4*)&zs[w][ng * 2 + i][og * 8 + 4] = hi;
        }

        // layer l3: c[2][8] = z[2][128] @ Wl3 tile
        float c[2][8];
#pragma unroll
        for (int i = 0; i < 2; ++i)
#pragma unroll
            for (int j = 0; j < 8; ++j) c[i][j] = sB3[og * 8 + j];
#pragma unroll 8
        for (int k = 0; k < 128; ++k) {
            float4 w0 = *(const float4*)&sW3[k * 128 + og * 8];
            float4 w1 = *(const float4*)&sW3[k * 128 + og * 8 + 4];
            float z0 = zs[w][ng * 2 + 0][k];
            float z1 = zs[w][ng * 2 + 1][k];
            c[0][0] = fmaf(z0, w0.x, c[0][0]); c[0][1] = fmaf(z0, w0.y, c[0][1]);
            c[0][2] = fmaf(z0, w0.z, c[0][2]); c[0][3] = fmaf(z0, w0.w, c[0][3]);
            c[0][4] = fmaf(z0, w1.x, c[0][4]); c[0][5] = fmaf(z0, w1.y, c[0][5]);
            c[0][6] = fmaf(z0, w1.z, c[0][6]); c[0][7] = fmaf(z0, w1.w, c[0][7]);
            c[1][0] = fmaf(z1, w0.x, c[1][0]); c[1][1] = fmaf(z1, w0.y, c[1][1]);
            c[1][2] = fmaf(z1, w0.z, c[1][2]); c[1][3] = fmaf(z1, w0.w, c[1][3]);
            c[1][4] = fmaf(z1, w1.x, c[1][4]); c[1][5] = fmaf(z1, w1.y, c[1][5]);
            c[1][6] = fmaf(z1, w1.z, c[1][6]); c[1][7] = fmaf(z1, w1.w, c[1][7]);
        }

        // layer l4: relu then dot with Wl4, reduce across og (low 4 lane bits)
#pragma unroll
        for (int i = 0; i < 2; ++i) {
            float p = 0.f;
#pragma unroll
            for (int j = 0; j < 8; ++j) {
                float v = c[i][j] > 0.f ? c[i][j] : 0.f;
                p = fmaf(v, sW4[og * 8 + j], p);
            }
            p += __shfl_xor(p, 1);
            p += __shfl_xor(p, 2);
            p += __shfl_xor(p, 4);
            p += __shfl_xor(p, 8);
            int node = base + ng * 2 + i;
            if (og == 0 && node < n) out[node] = p + blast;
        }
    }
}

extern "C" void kernel_launch(void* const* d_in, const int* in_sizes, int n_in,
                              void* d_out, int out_size, void* d_ws, size_t ws_size,
                              hipStream_t stream)
{
    const float* x   = (const float*)d_in[0];
    const void*  ei  = d_in[1];
    const float* W1  = (const float*)d_in[2];
    const float* b1  = (const float*)d_in[3];
    const float* W2  = (const float*)d_in[4];
    const float* b2  = (const float*)d_in[5];
    const float* W3  = (const float*)d_in[6];
    const float* b3  = (const float*)d_in[7];
    const float* Wl2 = (const float*)d_in[8];
    const float* bl2 = (const float*)d_in[9];
    const float* Wl3 = (const float*)d_in[10];
    const float* bl3 = (const float*)d_in[11];
    const float* Wl4 = (const float*)d_in[12];
    const float* bl4 = (const float*)d_in[13];
    float* out = (float*)d_out;

    int n        = in_sizes[0] / 9;          // 250000
    long long e2 = (long long)in_sizes[1];   // 2*E
    long long E  = e2 / 2;

    char* ws = (char*)d_ws;
    size_t off = 0;
    int* flag     = (int*)(ws + off); off += 256;
    int* partials = (int*)(ws + off); off += 8192;
    int* degi     = (int*)(ws + off); off += (size_t)n * 4;      off = (off + 255) & ~(size_t)255;
    int* row_off  = (int*)(ws + off); off += (size_t)n * 4;      off = (off + 255) & ~(size_t)255;
    int* cursor   = (int*)(ws + off); off += (size_t)n * 4;      off = (off + 255) & ~(size_t)255;
    float* dinv   = (float*)(ws + off); off += (size_t)n * 4;    off = (off + 255) & ~(size_t)255;
    int* ssrc     = (int*)(ws + off); off += (size_t)E * 4;      off = (off + 255) & ~(size_t)255;
    int* edges32  = (int*)(ws + off);                            // 2E*4 bytes
    // hs/agg alias the edges32 region (edges32 dead after k_fill)
    float* hs  = (float*)edges32;
    float* agg = hs + (size_t)n * 16;

    const int* src32 = edges32;
    const int* dst32 = edges32 + E;

    int nb_n  = (n + 255) / 256;
    int nb_e  = (int)((E + 255) / 256);
    int nb_e2 = (int)((e2 + 255) / 256);

    k_detect<<<1, 64, 0, stream>>>(ei, flag, n);
    k_convert<<<nb_e2, 256, 0, stream>>>(ei, flag, edges32, e2);

    hipMemsetAsync(degi, 0, (size_t)n * 4, stream);
    k_hist<<<nb_e, 256, 0, stream>>>(dst32, degi, E);
    k_scan1<<<nb_n, 256, 0, stream>>>(degi, row_off, partials, n);
    k_scan2<<<1, 1024, 0, stream>>>(partials, nb_n);
    k_scan3<<<nb_n, 256, 0, stream>>>(row_off, cursor, partials, n);
    k_dinv<<<nb_n, 256, 0, stream>>>(degi, dinv, n);
    k_fill<<<nb_e, 256, 0, stream>>>(src32, dst32, cursor, ssrc, E);

    int nb_g = (n + 3) / 4;   // one wave per node, 4 waves/block
    // layer 1
    k_lin1<<<nb_n, 256, 0, stream>>>(x, W1, dinv, hs, n);
    k_gather<<<nb_g, 256, 0, stream>>>(ssrc, row_off, degi, dinv, hs, agg, n);
    // layer 2
    k_lin_mid<<<nb_n, 256, 0, stream>>>(b1, W2, dinv, agg, hs, n);
    k_gather<<<nb_g, 256, 0, stream>>>(ssrc, row_off, degi, dinv, hs, agg, n);
    // layer 3
    k_lin_mid<<<nb_n, 256, 0, stream>>>(b2, W3, dinv, agg, hs, n);
    k_gather<<<nb_g, 256, 0, stream>>>(ssrc, row_off, degi, dinv, hs, agg, n);
    // MLP head
    k_mlp<<<512, 1024, 0, stream>>>(x, agg, b3, Wl2, bl2, Wl3, bl3, Wl4, bl4, out, n);
}

// Round 3
// 1322.181 us; speedup vs baseline: 1.3100x; 1.3100x over previous
//
#include <hip/hip_runtime.h>

// ---------------------------------------------------------------------------
// GCN: 3x GCNConv(9->16->16->16) + MLP(concat 25 ->128->128->1), N=250000,
// E=5,000,000 edges + self loops. f32 in/out; edge_index int32 OR int64
// (detected on device). CSR-by-dst gather aggregation (no float atomics) +
// register-blocked spill-free MLP (Wl3 from L2, 40KB LDS -> 4 blocks/CU).
// ---------------------------------------------------------------------------

__global__ __launch_bounds__(64) void k_detect(const void* __restrict__ edges,
                                               int* __restrict__ flag, int n_nodes)
{
    if (threadIdx.x == 0 && blockIdx.x == 0) {
        const long long* p = (const long long*)edges;
        int is64 = 1;
        for (int i = 0; i < 16; ++i) {
            long long v = p[i];
            if (v < 0 || v >= (long long)n_nodes) is64 = 0;
        }
        *flag = is64;
    }
}

// convert (x4 vectorized) + fused dst-degree histogram
__global__ __launch_bounds__(256) void k_convert_hist(const void* __restrict__ edges,
                                                      const int* __restrict__ flag,
                                                      int* __restrict__ out,
                                                      int* __restrict__ degi,
                                                      long long E)
{
    long long total = E * 2;
    long long i0 = ((long long)blockIdx.x * 256 + threadIdx.x) * 4;
    if (i0 >= total) return;
    int v0, v1, v2, v3;
    if (i0 + 4 <= total) {
        if (*flag) {
            longlong4 q = *((const longlong4*)((const long long*)edges + i0));
            v0 = (int)q.x; v1 = (int)q.y; v2 = (int)q.z; v3 = (int)q.w;
        } else {
            int4 q = *((const int4*)((const int*)edges + i0));
            v0 = q.x; v1 = q.y; v2 = q.z; v3 = q.w;
        }
        *(int4*)&out[i0] = make_int4(v0, v1, v2, v3);
        if (i0 >= E) {          // whole quad in dst half (E multiple of 4 anyway)
            atomicAdd(&degi[v0], 1);
            atomicAdd(&degi[v1], 1);
            atomicAdd(&degi[v2], 1);
            atomicAdd(&degi[v3], 1);
        } else if (i0 + 4 > E) {
            if (i0 + 0 >= E) atomicAdd(&degi[v0], 1);
            if (i0 + 1 >= E) atomicAdd(&degi[v1], 1);
            if (i0 + 2 >= E) atomicAdd(&degi[v2], 1);
            if (i0 + 3 >= E) atomicAdd(&degi[v3], 1);
        }
    } else {
        for (long long i = i0; i < total; ++i) {
            int v = (*flag) ? (int)((const long long*)edges)[i]
                            : ((const int*)edges)[i];
            out[i] = v;
            if (i >= E) atomicAdd(&degi[v], 1);
        }
    }
}

// exclusive scan, stage 1: per-256-chunk scan + per-block totals
__global__ __launch_bounds__(256) void k_scan1(const int* __restrict__ degi,
                                               int* __restrict__ excl,
                                               int* __restrict__ partials, int n)
{
    __shared__ int s[256];
    int tid = threadIdx.x;
    int i = blockIdx.x * 256 + tid;
    int v = (i < n) ? degi[i] : 0;
    s[tid] = v;
    __syncthreads();
#pragma unroll
    for (int off = 1; off < 256; off <<= 1) {
        int t = (tid >= off) ? s[tid - off] : 0;
        __syncthreads();
        s[tid] += t;
        __syncthreads();
    }
    if (i < n) excl[i] = s[tid] - v;
    if (tid == 255) partials[blockIdx.x] = s[255];
}

// stage 2: single block, exclusive scan of partials
__global__ __launch_bounds__(1024) void k_scan2(int* __restrict__ p, int nb)
{
    __shared__ int s[1024];
    __shared__ int carry_s;
    int t = threadIdx.x;
    if (t == 0) carry_s = 0;
    __syncthreads();
    for (int base = 0; base < nb; base += 1024) {
        int idx = base + t;
        int v = (idx < nb) ? p[idx] : 0;
        s[t] = v;
        __syncthreads();
        for (int off = 1; off < 1024; off <<= 1) {
            int u = (t >= off) ? s[t - off] : 0;
            __syncthreads();
            s[t] += u;
            __syncthreads();
        }
        int carry = carry_s;
        if (idx < nb) p[idx] = carry + s[t] - v;
        __syncthreads();
        if (t == 0) carry_s += s[1023];
        __syncthreads();
    }
}

// stage 3: add block offsets; produce row_off and cursor copy
__global__ __launch_bounds__(256) void k_scan3(int* __restrict__ row_off,
                                               int* __restrict__ cursor,
                                               const int* __restrict__ partials, int n)
{
    int i = blockIdx.x * 256 + threadIdx.x;
    if (i < n) {
        int v = row_off[i] + partials[blockIdx.x];
        row_off[i] = v;
        cursor[i]  = v;
    }
}

__global__ __launch_bounds__(256) void k_dinv(const int* __restrict__ degi,
                                              float* __restrict__ dinv, int n)
{
    int i = blockIdx.x * 256 + threadIdx.x;
    if (i < n) dinv[i] = rsqrtf((float)(degi[i] + 1));   // +1 self loop
}

__global__ __launch_bounds__(256) void k_fill(const int* __restrict__ src,
                                              const int* __restrict__ dst,
                                              int* __restrict__ cursor,
                                              int* __restrict__ ssrc, long long e)
{
    long long i = (long long)blockIdx.x * 256 + threadIdx.x;
    if (i >= e) return;
    int d = dst[i];
    int pos = atomicAdd(&cursor[d], 1);
    ssrc[pos] = src[i];
}

// h = x @ W1 (9->16); hs = h * dinv
__global__ __launch_bounds__(256) void k_lin1(const float* __restrict__ x,
                                              const float* __restrict__ W1,
                                              const float* __restrict__ dinv,
                                              float* __restrict__ hs, int n)
{
    __shared__ float sW[144];
    if (threadIdx.x < 144) sW[threadIdx.x] = W1[threadIdx.x];
    __syncthreads();
    int i = blockIdx.x * 256 + threadIdx.x;
    if (i >= n) return;
    float xv[9];
#pragma unroll
    for (int k = 0; k < 9; ++k) xv[k] = x[(size_t)i * 9 + k];
    float di = dinv[i];
#pragma unroll
    for (int j = 0; j < 16; ++j) {
        float acc = 0.f;
#pragma unroll
        for (int k = 0; k < 9; ++k) acc = fmaf(xv[k], sW[k * 16 + j], acc);
        hs[(size_t)i * 16 + j] = acc * di;
    }
}

// t = relu(agg + bias); h = t @ W (16->16); hs = h * dinv
__global__ __launch_bounds__(256) void k_lin_mid(const float* __restrict__ bias,
                                                 const float* __restrict__ W,
                                                 const float* __restrict__ dinv,
                                                 const float* __restrict__ agg,
                                                 float* __restrict__ hs, int n)
{
    __shared__ float sW[256];
    __shared__ float sB[16];
    sW[threadIdx.x] = W[threadIdx.x];
    if (threadIdx.x < 16) sB[threadIdx.x] = bias[threadIdx.x];
    __syncthreads();
    int i = blockIdx.x * 256 + threadIdx.x;
    if (i >= n) return;
    float t[16];
#pragma unroll
    for (int k = 0; k < 16; ++k) {
        float v = agg[(size_t)i * 16 + k] + sB[k];
        t[k] = v > 0.f ? v : 0.f;
    }
    float di = dinv[i];
#pragma unroll
    for (int j = 0; j < 16; ++j) {
        float acc = 0.f;
#pragma unroll
        for (int k = 0; k < 16; ++k) acc = fmaf(t[k], sW[k * 16 + j], acc);
        hs[(size_t)i * 16 + j] = acc * di;
    }
}

// One wave per node. lane = slot*16+k (4 edge slots x 16 feats).
__global__ __launch_bounds__(256) void k_gather(const int* __restrict__ ssrc,
                                                const int* __restrict__ row_off,
                                                const int* __restrict__ degi,
                                                const float* __restrict__ dinv,
                                                const float* __restrict__ hs,
                                                float* __restrict__ agg, int n)
{
    int wid = (int)(((long long)blockIdx.x * 256 + threadIdx.x) >> 6);
    if (wid >= n) return;
    int lane = threadIdx.x & 63;
    int slot = lane >> 4;
    int k    = lane & 15;
    int start = row_off[wid];
    int deg   = degi[wid];
    float sum = (slot == 0) ? hs[(size_t)wid * 16 + k] : 0.f;   // self loop
    for (int e = slot; e < deg; e += 4) {
        int s = ssrc[start + e];
        sum += hs[(size_t)s * 16 + k];
    }
    sum += __shfl_xor(sum, 16);
    sum += __shfl_xor(sum, 32);
    if (slot == 0) agg[(size_t)wid * 16 + k] = sum * dinv[wid];
}

// MLP head: feat=[x(9),relu(agg3+b3)(16)]; z=relu(feat@Wl2+bl2);
// z2=relu(z@Wl3+bl3); out=z2@Wl4+bl4.
// 256 thr = 4 waves; each wave owns a 16-node tile. lane=(ng,og): og in
// [0,16) -> 8 consecutive outputs; ng in [0,4) -> 4 nodes. Weights from
// global (L1/L2); only z + feat staged in LDS (40KB -> 4 blocks/CU).
__global__ __launch_bounds__(256, 4) void k_mlp(const float* __restrict__ x,
                                                const float* __restrict__ agg3,
                                                const float* __restrict__ b3,
                                                const float* __restrict__ Wl2,
                                                const float* __restrict__ bl2,
                                                const float* __restrict__ Wl3,
                                                const float* __restrict__ bl3,
                                                const float* __restrict__ Wl4,
                                                const float* __restrict__ bl4,
                                                float* __restrict__ out, int n)
{
    __shared__ __align__(16) float zs[4][16][132];     // 33792 B (padded stride)
    __shared__ __align__(16) float sfeat[4][16][28];   //  7168 B

    int tid  = threadIdx.x;
    int w    = tid >> 6;
    int lane = tid & 63;
    int og   = lane & 15;
    int ng   = lane >> 4;
    int base = (blockIdx.x * 4 + w) * 16;

    // stage features for this wave's 16 nodes
    for (int idx = lane; idx < 16 * 25; idx += 64) {
        int nn = idx / 25, f = idx - nn * 25;
        int node = base + nn;
        float v = 0.f;
        if (node < n) {
            if (f < 9) v = x[(size_t)node * 9 + f];
            else {
                float t = agg3[(size_t)node * 16 + (f - 9)] + b3[f - 9];
                v = t > 0.f ? t : 0.f;
            }
        }
        sfeat[w][nn][f] = v;
    }
    __syncthreads();

    float acc[4][8];
    // ---- layer l2: feat[16][25] @ Wl2[25][128] -> zs ----
    {
        float4 b0 = *(const float4*)&bl2[og * 8];
        float4 b1 = *(const float4*)&bl2[og * 8 + 4];
#pragma unroll
        for (int i = 0; i < 4; ++i) {
            acc[i][0] = b0.x; acc[i][1] = b0.y; acc[i][2] = b0.z; acc[i][3] = b0.w;
            acc[i][4] = b1.x; acc[i][5] = b1.y; acc[i][6] = b1.z; acc[i][7] = b1.w;
        }
    }
#pragma unroll
    for (int k = 0; k < 25; ++k) {
        float4 w0 = *(const float4*)&Wl2[k * 128 + og * 8];
        float4 w1 = *(const float4*)&Wl2[k * 128 + og * 8 + 4];
#pragma unroll
        for (int i = 0; i < 4; ++i) {
            float f = sfeat[w][ng * 4 + i][k];
            acc[i][0] = fmaf(f, w0.x, acc[i][0]); acc[i][1] = fmaf(f, w0.y, acc[i][1]);
            acc[i][2] = fmaf(f, w0.z, acc[i][2]); acc[i][3] = fmaf(f, w0.w, acc[i][3]);
            acc[i][4] = fmaf(f, w1.x, acc[i][4]); acc[i][5] = fmaf(f, w1.y, acc[i][5]);
            acc[i][6] = fmaf(f, w1.z, acc[i][6]); acc[i][7] = fmaf(f, w1.w, acc[i][7]);
        }
    }
#pragma unroll
    for (int i = 0; i < 4; ++i) {
        float4 lo, hi;
        lo.x = acc[i][0] > 0.f ? acc[i][0] : 0.f; lo.y = acc[i][1] > 0.f ? acc[i][1] : 0.f;
        lo.z = acc[i][2] > 0.f ? acc[i][2] : 0.f; lo.w = acc[i][3] > 0.f ? acc[i][3] : 0.f;
        hi.x = acc[i][4] > 0.f ? acc[i][4] : 0.f; hi.y = acc[i][5] > 0.f ? acc[i][5] : 0.f;
        hi.z = acc[i][6] > 0.f ? acc[i][6] : 0.f; hi.w = acc[i][7] > 0.f ? acc[i][7] : 0.f;
        *(float4*)&zs[w][ng * 4 + i][og * 8]     = lo;
        *(float4*)&zs[w][ng * 4 + i][og * 8 + 4] = hi;
    }
    __syncthreads();

    // ---- layer l3: z[16][128] @ Wl3[128][128] ----
    {
        float4 b0 = *(const float4*)&bl3[og * 8];
        float4 b1 = *(const float4*)&bl3[og * 8 + 4];
#pragma unroll
        for (int i = 0; i < 4; ++i) {
            acc[i][0] = b0.x; acc[i][1] = b0.y; acc[i][2] = b0.z; acc[i][3] = b0.w;
            acc[i][4] = b1.x; acc[i][5] = b1.y; acc[i][6] = b1.z; acc[i][7] = b1.w;
        }
    }
#pragma unroll 2
    for (int k = 0; k < 128; ++k) {
        float4 w0 = *(const float4*)&Wl3[k * 128 + og * 8];
        float4 w1 = *(const float4*)&Wl3[k * 128 + og * 8 + 4];
#pragma unroll
        for (int i = 0; i < 4; ++i) {
            float z = zs[w][ng * 4 + i][k];
            acc[i][0] = fmaf(z, w0.x, acc[i][0]); acc[i][1] = fmaf(z, w0.y, acc[i][1]);
            acc[i][2] = fmaf(z, w0.z, acc[i][2]); acc[i][3] = fmaf(z, w0.w, acc[i][3]);
            acc[i][4] = fmaf(z, w1.x, acc[i][4]); acc[i][5] = fmaf(z, w1.y, acc[i][5]);
            acc[i][6] = fmaf(z, w1.z, acc[i][6]); acc[i][7] = fmaf(z, w1.w, acc[i][7]);
        }
    }

    // ---- layer l4: relu, dot with Wl4, reduce over og ----
    {
        float4 w40 = *(const float4*)&Wl4[og * 8];
        float4 w41 = *(const float4*)&Wl4[og * 8 + 4];
        float bb = bl4[0];
#pragma unroll
        for (int i = 0; i < 4; ++i) {
            float p = 0.f;
            p = fmaf(acc[i][0] > 0.f ? acc[i][0] : 0.f, w40.x, p);
            p = fmaf(acc[i][1] > 0.f ? acc[i][1] : 0.f, w40.y, p);
            p = fmaf(acc[i][2] > 0.f ? acc[i][2] : 0.f, w40.z, p);
            p = fmaf(acc[i][3] > 0.f ? acc[i][3] : 0.f, w40.w, p);
            p = fmaf(acc[i][4] > 0.f ? acc[i][4] : 0.f, w41.x, p);
            p = fmaf(acc[i][5] > 0.f ? acc[i][5] : 0.f, w41.y, p);
            p = fmaf(acc[i][6] > 0.f ? acc[i][6] : 0.f, w41.z, p);
            p = fmaf(acc[i][7] > 0.f ? acc[i][7] : 0.f, w41.w, p);
            p += __shfl_xor(p, 1);
            p += __shfl_xor(p, 2);
            p += __shfl_xor(p, 4);
            p += __shfl_xor(p, 8);
            int node = base + ng * 4 + i;
            if (og == 0 && node < n) out[node] = p + bb;
        }
    }
}

extern "C" void kernel_launch(void* const* d_in, const int* in_sizes, int n_in,
                              void* d_out, int out_size, void* d_ws, size_t ws_size,
                              hipStream_t stream)
{
    const float* x   = (const float*)d_in[0];
    const void*  ei  = d_in[1];
    const float* W1  = (const float*)d_in[2];
    const float* b1  = (const float*)d_in[3];
    const float* W2  = (const float*)d_in[4];
    const float* b2  = (const float*)d_in[5];
    const float* W3  = (const float*)d_in[6];
    const float* b3  = (const float*)d_in[7];
    const float* Wl2 = (const float*)d_in[8];
    const float* bl2 = (const float*)d_in[9];
    const float* Wl3 = (const float*)d_in[10];
    const float* bl3 = (const float*)d_in[11];
    const float* Wl4 = (const float*)d_in[12];
    const float* bl4 = (const float*)d_in[13];
    float* out = (float*)d_out;

    int n        = in_sizes[0] / 9;          // 250000
    long long e2 = (long long)in_sizes[1];   // 2*E
    long long E  = e2 / 2;

    char* ws = (char*)d_ws;
    size_t off = 0;
    int* flag     = (int*)(ws + off); off += 256;
    int* partials = (int*)(ws + off); off += 8192;
    int* degi     = (int*)(ws + off); off += (size_t)n * 4;      off = (off + 255) & ~(size_t)255;
    int* row_off  = (int*)(ws + off); off += (size_t)n * 4;      off = (off + 255) & ~(size_t)255;
    int* cursor   = (int*)(ws + off); off += (size_t)n * 4;      off = (off + 255) & ~(size_t)255;
    float* dinv   = (float*)(ws + off); off += (size_t)n * 4;    off = (off + 255) & ~(size_t)255;
    int* ssrc     = (int*)(ws + off); off += (size_t)E * 4;      off = (off + 255) & ~(size_t)255;
    int* edges32  = (int*)(ws + off);                            // 2E*4 bytes
    // hs/agg alias the edges32 region (edges32 dead after k_fill)
    float* hs  = (float*)edges32;
    float* agg = hs + (size_t)n * 16;

    const int* src32 = edges32;
    const int* dst32 = edges32 + E;

    int nb_n  = (n + 255) / 256;
    int nb_e  = (int)((E + 255) / 256);
    int nb_c  = (int)((e2 / 4 + 255) / 256);

    k_detect<<<1, 64, 0, stream>>>(ei, flag, n);
    hipMemsetAsync(degi, 0, (size_t)n * 4, stream);
    k_convert_hist<<<nb_c, 256, 0, stream>>>(ei, flag, edges32, degi, E);

    k_scan1<<<nb_n, 256, 0, stream>>>(degi, row_off, partials, n);
    k_scan2<<<1, 1024, 0, stream>>>(partials, nb_n);
    k_scan3<<<nb_n, 256, 0, stream>>>(row_off, cursor, partials, n);
    k_dinv<<<nb_n, 256, 0, stream>>>(degi, dinv, n);
    k_fill<<<nb_e, 256, 0, stream>>>(src32, dst32, cursor, ssrc, E);

    int nb_g = (n + 3) / 4;   // one wave per node, 4 waves/block
    // layer 1
    k_lin1<<<nb_n, 256, 0, stream>>>(x, W1, dinv, hs, n);
    k_gather<<<nb_g, 256, 0, stream>>>(ssrc, row_off, degi, dinv, hs, agg, n);
    // layer 2
    k_lin_mid<<<nb_n, 256, 0, stream>>>(b1, W2, dinv, agg, hs, n);
    k_gather<<<nb_g, 256, 0, stream>>>(ssrc, row_off, degi, dinv, hs, agg, n);
    // layer 3
    k_lin_mid<<<nb_n, 256, 0, stream>>>(b2, W3, dinv, agg, hs, n);
    k_gather<<<nb_g, 256, 0, stream>>>(ssrc, row_off, degi, dinv, hs, agg, n);
    // MLP head
    k_mlp<<<(n + 63) / 64, 256, 0, stream>>>(x, agg, b3, Wl2, bl2, Wl3, bl3, Wl4, bl4,
                                             out, n);
}